// Round 4
// baseline (1953.770 us; speedup 1.0000x reference)
//
#include <hip/hip_runtime.h>

typedef float v2f __attribute__((ext_vector_type(2)));

#define QN 8192   // trajectories
#define MN 2048   // time steps
#define HN 64     // hidden units
#define LPT 16    // lanes per trajectory
#define UPL 4     // hidden units per lane

// DPP butterfly add within each 16-lane group. Full-rate VALU, no LDS.
// Identical sequence to the R2/R3 versions that passed.
template <int CTRL>
__device__ __forceinline__ float dpp_add(float v) {
    int m = __builtin_amdgcn_update_dpp(0, __float_as_int(v), CTRL, 0xf, 0xf, true);
    return v + __int_as_float(m);
}
#define DPP_QUAD_XOR1 0xB1   // quad_perm [1,0,3,2]
#define DPP_QUAD_XOR2 0x4E   // quad_perm [2,3,0,1]
#define DPP_HALF_MIRR 0x141  // row_half_mirror
#define DPP_ROW_MIRR  0x140  // row_mirror

__device__ __forceinline__ v2f vfma(v2f a, v2f b, v2f c) {
    return __builtin_elementwise_fma(a, b, c);
}

__global__ __launch_bounds__(256, 2) void rk4_nss_kernel(
    const float* __restrict__ x0p,   // (Q,2)
    const float* __restrict__ up,    // (M,Q)
    const float* __restrict__ W1,    // (3,H)
    const float* __restrict__ b1,    // (H)
    const float* __restrict__ W2,    // (H,2)
    const float* __restrict__ b2,    // (2)
    float* __restrict__ out)         // (M,Q,2)
{
    const int tid  = blockIdx.x * 256 + threadIdx.x;
    const int lane = threadIdx.x & (LPT - 1);
    const int traj = tid >> 4;
    if (traj >= QN) return;

    const float SC = 2.8853900817779268f;  // 2*log2(e): e^{2x} = 2^(SC*x)
    const float CL = 27.0f;                // |scaled pre| clamp: tanh saturated,
                                           // quad den-product <= 3.3e32 (finite)

    // Lane owns units jk = lane + k*16, packed as A=(k0,k1), B=(k2,k3).
    // W1,b1 pre-scaled by SC; accumulate inv*( -2*W2 ) and add c = b2 + sum(W2).
    v2f w10A, w10B, w11A, w11B, w12A, w12B, bsA, bsB, w20A, w20B, w21A, w21B;
#pragma unroll
    for (int k = 0; k < 2; ++k) {
        const int jA = lane + k * LPT;            // k = 0,1
        const int jB = lane + (k + 2) * LPT;      // k = 2,3
        w10A[k] = W1[jA] * SC;           w10B[k] = W1[jB] * SC;
        w11A[k] = W1[HN + jA] * SC;      w11B[k] = W1[HN + jB] * SC;
        w12A[k] = W1[2 * HN + jA] * SC;  w12B[k] = W1[2 * HN + jB] * SC;
        bsA[k]  = b1[jA] * SC;           bsB[k]  = b1[jB] * SC;
        w20A[k] = -2.0f * W2[2 * jA];    w20B[k] = -2.0f * W2[2 * jB];
        w21A[k] = -2.0f * W2[2 * jA + 1]; w21B[k] = -2.0f * W2[2 * jB + 1];
    }
    v2f c2 = {b2[0], b2[1]};
    for (int j = 0; j < HN; ++j) {   // init only; W2 is 512 B, cache-hot
        c2.x += W2[2 * j];
        c2.y += W2[2 * j + 1];
    }
    const v2f sixth2 = {1.0f / 6.0f, 1.0f / 6.0f};

    v2f x = {x0p[2 * traj], x0p[2 * traj + 1]};
    float ucur = up[traj];

    v2f pbA, pbB;  // u-dependent preactivation part, constant across 4 fevals

    auto feval = [&](v2f xi) -> v2f {
        v2f ia2 = {xi.x, xi.x};
        v2f ib2 = {xi.y, xi.y};
        v2f pA = vfma(w10A, ia2, vfma(w11A, ib2, pbA));
        v2f pB = vfma(w10B, ia2, vfma(w11B, ib2, pbB));
        // scalar med3 clamp (no packed f32 med3/min/max on CDNA)
        pA.x = __builtin_amdgcn_fmed3f(pA.x, -CL, CL);
        pA.y = __builtin_amdgcn_fmed3f(pA.y, -CL, CL);
        pB.x = __builtin_amdgcn_fmed3f(pB.x, -CL, CL);
        pB.y = __builtin_amdgcn_fmed3f(pB.y, -CL, CL);
        v2f dA = {__builtin_amdgcn_exp2f(pA.x) + 1.0f,
                  __builtin_amdgcn_exp2f(pA.y) + 1.0f};
        v2f dB = {__builtin_amdgcn_exp2f(pB.x) + 1.0f,
                  __builtin_amdgcn_exp2f(pB.y) + 1.0f};
        // Quad-batched reciprocal: 1 rcp for 4 denominators (trans ~20cy each).
        float d01 = dA.x * dA.y;
        float d23 = dB.x * dB.y;
        float r   = __builtin_amdgcn_rcpf(d01 * d23);
        float r01 = r * d23;
        float r23 = r * d01;
        v2f invA = {r01 * dA.y, r01 * dA.x};   // pk_mul w/ op_sel swap (or 2 mul)
        v2f invB = {r23 * dB.y, r23 * dB.x};
        // tanh_k = 1 + inv_k*(-2); the "+1" parts are folded into c2.
        v2f a0 = vfma(invB, w20B, invA * w20A);
        v2f a1 = vfma(invB, w21B, invA * w21A);
        float p0 = a0.x + a0.y;
        float p1 = a1.x + a1.y;
        p0 = dpp_add<DPP_QUAD_XOR1>(p0);  p1 = dpp_add<DPP_QUAD_XOR1>(p1);
        p0 = dpp_add<DPP_QUAD_XOR2>(p0);  p1 = dpp_add<DPP_QUAD_XOR2>(p1);
        p0 = dpp_add<DPP_HALF_MIRR>(p0);  p1 = dpp_add<DPP_HALF_MIRR>(p1);
        p0 = dpp_add<DPP_ROW_MIRR>(p0);   p1 = dpp_add<DPP_ROW_MIRR>(p1);
        v2f kv = {p0, p1};
        return kv + c2;
    };

    for (int t = 0; t < MN; ++t) {
        // Output is the state BEFORE the update.
        if (lane == 0) {
            *reinterpret_cast<v2f*>(out + 2 * (t * QN + traj)) = x;
        }
        // Prefetch next step's input (hidden under the 4 fevals).
        const float unext = (t + 1 < MN) ? up[(t + 1) * QN + traj] : 0.0f;

        v2f u2 = {ucur, ucur};
        pbA = vfma(w12A, u2, bsA);
        pbB = vfma(w12B, u2, bsB);

        v2f k1 = feval(x);
        v2f k2 = feval(vfma((v2f){0.5f, 0.5f}, k1, x));
        v2f k3 = feval(vfma((v2f){0.5f, 0.5f}, k2, x));
        v2f k4 = feval(x + k3);

        v2f tt = k2 + k3;
        v2f ss = k1 + k4;
        x = vfma(sixth2, vfma((v2f){2.0f, 2.0f}, tt, ss), x);
        ucur = unext;
    }
}

extern "C" void kernel_launch(void* const* d_in, const int* in_sizes, int n_in,
                              void* d_out, int out_size, void* d_ws, size_t ws_size,
                              hipStream_t stream) {
    const float* x0 = (const float*)d_in[0];
    const float* u  = (const float*)d_in[1];
    const float* W1 = (const float*)d_in[2];
    const float* b1 = (const float*)d_in[3];
    const float* W2 = (const float*)d_in[4];
    const float* b2 = (const float*)d_in[5];
    float* out = (float*)d_out;

    const int threads = 256;
    const int blocks  = (QN * LPT) / threads;
    rk4_nss_kernel<<<blocks, threads, 0, stream>>>(x0, u, W1, b1, W2, b2, out);
}

// Round 5
// 1947.466 us; speedup vs baseline: 1.0032x; 1.0032x over previous
//
#include <hip/hip_runtime.h>

#define QN 8192   // trajectories
#define MN 2048   // time steps
#define HN 64     // hidden units
#define LPT 16    // lanes per trajectory
#define UPL 4     // hidden units per lane

// DPP butterfly add within each 16-lane group. Full-rate VALU, no LDS.
// Identical sequence to the R2/R3 versions that passed.
template <int CTRL>
__device__ __forceinline__ float dpp_add(float v) {
    int m = __builtin_amdgcn_update_dpp(0, __float_as_int(v), CTRL, 0xf, 0xf, true);
    return v + __int_as_float(m);
}
#define DPP_QUAD_XOR1 0xB1   // quad_perm [1,0,3,2]
#define DPP_QUAD_XOR2 0x4E   // quad_perm [2,3,0,1]
#define DPP_HALF_MIRR 0x141  // row_half_mirror
#define DPP_ROW_MIRR  0x140  // row_mirror

__global__ __launch_bounds__(256, 2) void rk4_nss_kernel(
    const float* __restrict__ x0p,   // (Q,2)
    const float* __restrict__ up,    // (M,Q)
    const float* __restrict__ W1,    // (3,H)
    const float* __restrict__ b1,    // (H)
    const float* __restrict__ W2,    // (H,2)
    const float* __restrict__ b2,    // (2)
    float* __restrict__ out)         // (M,Q,2)
{
    const int tid  = blockIdx.x * 256 + threadIdx.x;
    const int lane = threadIdx.x & (LPT - 1);
    const int traj = tid >> 4;
    if (traj >= QN) return;

    const float SC = 2.8853900817779268f;  // 2*log2(e): e^{2x} = 2^(SC*x)
    const float CL = 27.0f;  // clamp in scaled units: tanh(27/SC=9.36) == 1.0f
                             // exactly in f32, and 4*27 = 108 < 128 so the
                             // quad den-product below cannot overflow.

    // Per-lane weights: this lane owns hidden units j = lane + k*LPT.
    // W1,b1 pre-scaled by SC (exp arg needs no mul); tanh = 1 - 2/(e^{2x}+1)
    // with the "+1" parts folded into c0,c1 and inv*( -2*W2 ) accumulated.
    float ws10[UPL], ws11[UPL], ws12[UPL], bsb[UPL], w20n[UPL], w21n[UPL];
#pragma unroll
    for (int k = 0; k < UPL; ++k) {
        const int j = lane + k * LPT;
        ws10[k] = W1[j] * SC;
        ws11[k] = W1[HN + j] * SC;
        ws12[k] = W1[2 * HN + j] * SC;
        bsb[k]  = b1[j] * SC;
        w20n[k] = -2.0f * W2[2 * j];
        w21n[k] = -2.0f * W2[2 * j + 1];
    }
    float c0 = b2[0], c1 = b2[1];
    for (int j = 0; j < HN; ++j) {   // init-time only; W2 is 512 B, cache-hot
        c0 += W2[2 * j];
        c1 += W2[2 * j + 1];
    }

    float xa = x0p[2 * traj];
    float xb = x0p[2 * traj + 1];
    float ucur = up[traj];

    float2* outv = reinterpret_cast<float2*>(out);

    float pb[UPL];  // u-dependent preactivation part, constant across 4 fevals

    auto feval = [&](float ia, float ib, float& d0, float& d1) {
        float den[UPL];
#pragma unroll
        for (int k = 0; k < UPL; ++k) {
            float pre = fmaf(ws10[k], ia, fmaf(ws11[k], ib, pb[k]));
            pre = __builtin_amdgcn_fmed3f(pre, -CL, CL);
            den[k] = __builtin_amdgcn_exp2f(pre) + 1.0f;
        }
        // Quad-batched reciprocal: 1 rcp (trans op, ~20cy issue-block) for 4
        // denominators. Each den <= 2^27+1, product <= ~2^108: finite.
        float d01 = den[0] * den[1];
        float d23 = den[2] * den[3];
        float r   = __builtin_amdgcn_rcpf(d01 * d23);
        float r01 = r * d23;
        float r23 = r * d01;
        float inv0 = r01 * den[1];
        float inv1 = r01 * den[0];
        float inv2 = r23 * den[3];
        float inv3 = r23 * den[2];

        float p0 = fmaf(inv0, w20n[0],
                   fmaf(inv1, w20n[1],
                   fmaf(inv2, w20n[2], inv3 * w20n[3])));
        float p1 = fmaf(inv0, w21n[0],
                   fmaf(inv1, w21n[1],
                   fmaf(inv2, w21n[2], inv3 * w21n[3])));

        p0 = dpp_add<DPP_QUAD_XOR1>(p0);  p1 = dpp_add<DPP_QUAD_XOR1>(p1);
        p0 = dpp_add<DPP_QUAD_XOR2>(p0);  p1 = dpp_add<DPP_QUAD_XOR2>(p1);
        p0 = dpp_add<DPP_HALF_MIRR>(p0);  p1 = dpp_add<DPP_HALF_MIRR>(p1);
        p0 = dpp_add<DPP_ROW_MIRR>(p0);   p1 = dpp_add<DPP_ROW_MIRR>(p1);
        d0 = p0 + c0;
        d1 = p1 + c1;
    };

    for (int t = 0; t < MN; ++t) {
        // Output is the state BEFORE the update.
        if (lane == 0) {
            outv[t * QN + traj] = make_float2(xa, xb);
        }
        // Prefetch next step's input (hidden under the 4 fevals).
        const float unext = (t + 1 < MN) ? up[(t + 1) * QN + traj] : 0.0f;

#pragma unroll
        for (int k = 0; k < UPL; ++k)
            pb[k] = fmaf(ws12[k], ucur, bsb[k]);

        float k1a, k1b, k2a, k2b, k3a, k3b, k4a, k4b;
        feval(xa, xb, k1a, k1b);
        feval(fmaf(0.5f, k1a, xa), fmaf(0.5f, k1b, xb), k2a, k2b);
        feval(fmaf(0.5f, k2a, xa), fmaf(0.5f, k2b, xb), k3a, k3b);
        feval(xa + k3a, xb + k3b, k4a, k4b);

        float ta = k2a + k3a;
        float sa = k1a + k4a;
        xa = fmaf((1.0f / 6.0f), fmaf(2.0f, ta, sa), xa);
        float tb = k2b + k3b;
        float sb = k1b + k4b;
        xb = fmaf((1.0f / 6.0f), fmaf(2.0f, tb, sb), xb);
        ucur = unext;
    }
}

extern "C" void kernel_launch(void* const* d_in, const int* in_sizes, int n_in,
                              void* d_out, int out_size, void* d_ws, size_t ws_size,
                              hipStream_t stream) {
    const float* x0 = (const float*)d_in[0];
    const float* u  = (const float*)d_in[1];
    const float* W1 = (const float*)d_in[2];
    const float* b1 = (const float*)d_in[3];
    const float* W2 = (const float*)d_in[4];
    const float* b2 = (const float*)d_in[5];
    float* out = (float*)d_out;

    const int threads = 256;
    const int blocks  = (QN * LPT) / threads;
    rk4_nss_kernel<<<blocks, threads, 0, stream>>>(x0, u, W1, b1, W2, b2, out);
}